// Round 12
// baseline (374.172 us; speedup 1.0000x reference)
//
#include <hip/hip_runtime.h>
#include <math.h>

constexpr int Nn = 200000, Ee = 400000, Gg = 4096;

__device__ __forceinline__ float elu1(float v) {
    return v > 0.f ? v : __expf(v) - 1.f;
}

// ----------------------------------------------------------- zero hist ----
__global__ __launch_bounds__(256) void k_zero(int* __restrict__ hist) {
    int i = blockIdx.x * 256 + threadIdx.x;
    if (i < Gg) hist[i] = 0;
}

// ------------------------------------------- histogram + eb cache ---------
__global__ __launch_bounds__(256) void k_hist(const int* __restrict__ edges,
                                              const int* __restrict__ batch,
                                              int* __restrict__ hist,
                                              int* __restrict__ ebuf) {
    int e = blockIdx.x * 256 + threadIdx.x;
    if (e >= Ee) return;
    int eb = batch[edges[2 * e]];
    ebuf[e] = eb;
    atomicAdd(&hist[eb], 1);
}

// ------------------- exclusive scan (1 block, 256 thr, 16 bins/thread) ----
__global__ __launch_bounds__(256) void k_scan(const int* __restrict__ hist,
                                              int* __restrict__ offsets,
                                              int* __restrict__ cursor) {
    __shared__ int part[256];
    int t = threadIdx.x;
    int local[16];
    int s = 0;
#pragma unroll
    for (int j = 0; j < 16; ++j) { local[j] = s; s += hist[t * 16 + j]; }
    part[t] = s;
    __syncthreads();
    for (int off = 1; off < 256; off <<= 1) {
        int v = (t >= off) ? part[t - off] : 0;
        __syncthreads();
        part[t] += v;
        __syncthreads();
    }
    int pre = (t == 0) ? 0 : part[t - 1];
#pragma unroll
    for (int j = 0; j < 16; ++j) {
        int o = pre + local[j];
        offsets[t * 16 + j] = o;
        cursor[t * 16 + j]  = o;
    }
}

// ------------------------------------------------------------ scatter -----
__global__ __launch_bounds__(256) void k_scatter(const int* __restrict__ ebuf,
                                                 int* __restrict__ cursor,
                                                 int* __restrict__ order) {
    int e = blockIdx.x * 256 + threadIdx.x;
    if (e >= Ee) return;
    int p = atomicAdd(&cursor[ebuf[e]], 1);
    order[p] = e;
}

// --------------------- per-edge wave-uniform precompute: dist + 6 rbf -----
// 1 thread/edge; pos is 2.4 MB (L2-resident), gathers cheap.
__global__ __launch_bounds__(256) void k_rbf(const float* __restrict__ pos,
                                             const int* __restrict__ edges,
                                             float4* __restrict__ rbuf) {
    int e = blockIdx.x * 256 + threadIdx.x;
    if (e >= Ee) return;
    int2 ed = ((const int2*)edges)[e];
    int src = ed.x, dst = ed.y;
    float dx = pos[dst * 3 + 0] - pos[src * 3 + 0];
    float dy = pos[dst * 3 + 1] - pos[src * 3 + 1];
    float dz = pos[dst * 3 + 2] - pos[src * 3 + 2];
    float dist = fmaxf(sqrtf(dx * dx + dy * dy + dz * dz), 0.1f);
    float4 a, b4;
    a.x  = __expf(-0.5f * (dist - 0.f) * (dist - 0.f));
    a.y  = __expf(-0.5f * (dist - 1.f) * (dist - 1.f));
    a.z  = __expf(-0.5f * (dist - 2.f) * (dist - 2.f));
    a.w  = __expf(-0.5f * (dist - 3.f) * (dist - 3.f));
    b4.x = __expf(-0.5f * (dist - 4.f) * (dist - 4.f));
    b4.y = __expf(-0.5f * (dist - 5.f) * (dist - 5.f));
    b4.z = 0.f; b4.w = 0.f;
    rbuf[2 * e]     = a;
    rbuf[2 * e + 1] = b4;
}

// ------------------------------------------------------- h = x @ W + b ----
// Register-tiled LDS GEMM: block tile 128 nodes x 128 dims, K=64 (padded),
// thread tile 8x8. LDS quad layouts (node/dim idx, K-quad kq):
//   f4pos = kq*128 + ((p + kq) & 127),  p = (idx&7)*16 + (idx>>3)
// x-tile staged DIRECTLY from x: rows are contiguous, so the tile is the
// contiguous span x[base*63 .. base*63+8064); scatter by idx/63, idx%63.
// k=63 slots (kq=15,ki=3) are never written by staging -> zeroed once.
__global__ __launch_bounds__(256, 2) void k_h(const float* __restrict__ x,
                                              const float* __restrict__ W,
                                              const float* __restrict__ b,
                                              float* __restrict__ h, int N) {
    __shared__ float4 xs[2048];   // 32 KB
    __shared__ float4 ws[2048];   // 32 KB
    int t  = threadIdx.x;
    int tn = t & 15;              // dim-group: dims d = tn*8 + i
    int tm = t >> 4;              // node-group: nodes n = tm*8 + j
    float* xsf = (float*)xs;

    // ---- stage W once (transpose scatter, amortized over tiles) ----
    {
        float* wsf = (float*)ws;
        for (int i = t; i < 8192; i += 256) {     // i = k*128 + d
            int k = i >> 7, d = i & 127;
            float v  = (k < 63) ? W[k * 128 + d] : 0.f;
            int  pd  = ((d & 7) << 4) | (d >> 3);
            int  kq  = k >> 2, ki = k & 3;
            wsf[(((kq << 7) + ((pd + kq) & 127)) << 2) + ki] = v;
        }
    }
    // ---- zero the k=63 slot of every node row, once (never re-dirtied) ----
    if (t < 128) {
        int pn = ((t & 7) << 4) | (t >> 3);
        xsf[(((15 << 7) + ((pn + 15) & 127)) << 2) + 3] = 0.f;
    }
    float bd[8];
#pragma unroll
    for (int i = 0; i < 8; ++i) bd[i] = b[tn * 8 + i];

    int ntiles = (N + 127) >> 7;
    for (int tile = blockIdx.x; tile < ntiles; tile += gridDim.x) {
        int base = tile << 7;
        __syncthreads();   // xs readers of previous tile done (fences W/zero too)
        // ---- stage x tile: 8064 floats, coalesced scalar loads ----
        {
            const float* xg = x + (size_t)base * 63;
            int lim = Nn * 63 - base * 63;   // valid floats remaining
            for (int idx = t; idx < 8064; idx += 256) {
                float v = (idx < lim) ? xg[idx] : 0.f;
                int n  = idx / 63;
                int k  = idx - n * 63;
                int pn = ((n & 7) << 4) | (n >> 3);
                int kq = k >> 2, ki = k & 3;
                xsf[(((kq << 7) + ((pn + kq) & 127)) << 2) + ki] = v;
            }
        }
        __syncthreads();

        float acc[8][8];
#pragma unroll
        for (int j = 0; j < 8; ++j)
#pragma unroll
            for (int i = 0; i < 8; ++i) acc[j][i] = bd[i];

#pragma unroll 2
        for (int kq = 0; kq < 16; ++kq) {
            float4 af[8], bf[8];
#pragma unroll
            for (int j = 0; j < 8; ++j)
                af[j] = xs[(kq << 7) + (((j << 4) + tm + kq) & 127)];
#pragma unroll
            for (int i = 0; i < 8; ++i)
                bf[i] = ws[(kq << 7) + (((i << 4) + tn + kq) & 127)];
#pragma unroll
            for (int j = 0; j < 8; ++j)
#pragma unroll
                for (int i = 0; i < 8; ++i) {
                    acc[j][i] = fmaf(af[j].x, bf[i].x, acc[j][i]);
                    acc[j][i] = fmaf(af[j].y, bf[i].y, acc[j][i]);
                    acc[j][i] = fmaf(af[j].z, bf[i].z, acc[j][i]);
                    acc[j][i] = fmaf(af[j].w, bf[i].w, acc[j][i]);
                }
        }

        // ---- write h: 2 float4 per node row, coalesced across tn ----
#pragma unroll
        for (int j = 0; j < 8; ++j) {
            int n = base + tm * 8 + j;
            if (n < N) {
                float4 o0 = {acc[j][0], acc[j][1], acc[j][2], acc[j][3]};
                float4 o1 = {acc[j][4], acc[j][5], acc[j][6], acc[j][7]};
                float4* dst = (float4*)(h + (size_t)n * 128 + tn * 8);
                dst[0] = o0;
                dst[1] = o1;
            }
        }
    }
}

// --------------------------- per-segment reduction (no float atomics) -----
// one block per segment; 4 waves round-robin; lane owns dims (2l, 2l+1).
// rbf factors precomputed (wave-uniform broadcast loads).
__global__ __launch_bounds__(256) void k_reduce(
    const float* __restrict__ h, const float4* __restrict__ rbuf,
    const float* __restrict__ attn,
    const float* __restrict__ W_rbf,
    const float* __restrict__ W_read, const float* __restrict__ b_read,
    const int* __restrict__ edges, const int* __restrict__ order,
    const int* __restrict__ offsets, const int* __restrict__ hist,
    float* __restrict__ out) {

    __shared__ float lsum[4][256];
    __shared__ float lmax[4][256];

    int g    = blockIdx.x;
    int t    = threadIdx.x;
    int lane = t & 63;
    int wv   = t >> 6;
    int start = offsets[g];
    int cnt   = hist[g];

    const float2* Wr = (const float2*)W_rbf;
    float2 w0 = Wr[0 * 64 + lane];
    float2 w1 = Wr[1 * 64 + lane];
    float2 w2 = Wr[2 * 64 + lane];
    float2 w3 = Wr[3 * 64 + lane];
    float2 w4 = Wr[4 * 64 + lane];
    float2 w5 = Wr[5 * 64 + lane];
    float2 at = ((const float2*)attn)[lane];
    float2 wr = ((const float2*)W_read)[lane];
    float  br = b_read[0];

    float sx = 0.f, sy = 0.f;
    float mx = -INFINITY, my = -INFINITY;

    for (int i = wv; i < cnt; i += 4) {
        int e   = order[start + i];
        int2 ed = ((const int2*)edges)[e];
        float4 rA = rbuf[2 * e];
        float4 rB = rbuf[2 * e + 1];

        float2 hs = ((const float2*)(h + (size_t)ed.x * 128))[lane];
        float2 hd = ((const float2*)(h + (size_t)ed.y * 128))[lane];
        float hex = elu1(hs.x + hd.x);
        float hey = elu1(hs.y + hd.y);

        float gx = rA.x * w0.x + rA.y * w1.x + rA.z * w2.x +
                   rA.w * w3.x + rB.x * w4.x + rB.y * w5.x;
        float gy = rA.x * w0.y + rA.y * w1.y + rA.z * w2.y +
                   rA.w * w3.y + rB.x * w4.y + rB.y * w5.y;

        float ax = elu1(hex * gx * at.x);
        float ay = elu1(hey * gy * at.y);

        float p = ax * wr.x + ay * wr.y;
#pragma unroll
        for (int off = 32; off; off >>= 1) p += __shfl_xor(p, off);
        float score = 1.f / (1.f + __expf(-(p + br)));

        sx = fmaf(ax, score, sx);
        sy = fmaf(ay, score, sy);
        mx = fmaxf(mx, ax);
        my = fmaxf(my, ay);
    }

    lsum[wv][lane * 2 + 0] = sx;
    lsum[wv][lane * 2 + 1] = sy;
    lmax[wv][lane * 2 + 0] = mx;
    lmax[wv][lane * 2 + 1] = my;
    __syncthreads();

    float r;
    if (t < 128) {
        r = lsum[0][t] + lsum[1][t] + lsum[2][t] + lsum[3][t];
    } else {
        int d = t - 128;
        float m = fmaxf(fmaxf(lmax[0][d], lmax[1][d]),
                        fmaxf(lmax[2][d], lmax[3][d]));
        r = (m > -3.0e38f) ? m : 0.f;   // empty segment -> 0 (isfinite fixup)
    }
    out[g * 256 + t] = r;
}

// ---------------------------------------------------------------- host ---
extern "C" void kernel_launch(void* const* d_in, const int* in_sizes, int n_in,
                              void* d_out, int out_size, void* d_ws, size_t ws_size,
                              hipStream_t stream) {
    const float* x      = (const float*)d_in[0];
    const float* pos    = (const float*)d_in[1];
    const float* W      = (const float*)d_in[2];
    const float* b      = (const float*)d_in[3];
    const float* attn   = (const float*)d_in[4];
    const float* W_rbf  = (const float*)d_in[5];
    const float* W_read = (const float*)d_in[6];
    const float* b_read = (const float*)d_in[7];
    const int*   edges  = (const int*)d_in[8];
    const int*   batch  = (const int*)d_in[9];
    float* out = (float*)d_out;

    char* p = (char*)d_ws;
    float*  h       = (float*)p;                p += (size_t)Nn * 128 * 4;  // 102.4 MB
    float4* rbuf    = (float4*)p;               p += (size_t)Ee * 32;       //  12.8 MB
    int*    hist    = (int*)p;                  p += Gg * 4;
    int*    offsets = (int*)p;                  p += Gg * 4;
    int*    cursor  = (int*)p;                  p += Gg * 4;
    int*    ebuf    = (int*)p;                  p += Ee * 4;
    int*    order   = (int*)p;                  p += Ee * 4;

    k_zero<<<(Gg + 255) / 256, 256, 0, stream>>>(hist);
    k_hist<<<(Ee + 255) / 256, 256, 0, stream>>>(edges, batch, hist, ebuf);
    k_scan<<<1, 256, 0, stream>>>(hist, offsets, cursor);
    k_scatter<<<(Ee + 255) / 256, 256, 0, stream>>>(ebuf, cursor, order);
    k_rbf<<<(Ee + 255) / 256, 256, 0, stream>>>(pos, edges, rbuf);
    k_h<<<512, 256, 0, stream>>>(x, W, b, h, Nn);
    k_reduce<<<Gg, 256, 0, stream>>>(h, rbuf, attn, W_rbf, W_read, b_read,
                                     edges, order, offsets, hist, out);
}